// Round 8
// baseline (762.887 us; speedup 1.0000x reference)
//
#include <hip/hip_runtime.h>
#include <hip/hip_bf16.h>
#include <hip/hip_fp16.h>
#include <cstddef>

#define NEG_SLOPE 0.2f

typedef _Float16 half8 __attribute__((ext_vector_type(8)));
typedef float floatx4 __attribute__((ext_vector_type(4)));
typedef float floatx2 __attribute__((ext_vector_type(2)));

// ================= bucketed CSR build =================
// Bucket = 512 consecutive dst nodes. NB = ceil(N/512) (== 196 for N=100000, must be <= 256).
// part[] holds (src << 9) | (dst & 511) packed per edge, grouped by bucket.

__global__ __launch_bounds__(256) void bucket_hist_k(const int* __restrict__ dst, int E,
                                                     int* __restrict__ bhist, int NB) {
    __shared__ int lh[256];
    for (int t = threadIdx.x; t < 256; t += 256) lh[t] = 0;
    __syncthreads();
    int per = (E + gridDim.x - 1) / gridDim.x;
    int s = blockIdx.x * per;
    int e = min(s + per, E);
    for (int i = s + threadIdx.x; i < e; i += 256) atomicAdd(&lh[dst[i] >> 9], 1);
    __syncthreads();
    for (int t = threadIdx.x; t < NB; t += 256)
        if (lh[t]) atomicAdd(&bhist[t], lh[t]);
}

__global__ __launch_bounds__(256) void bucket_scan_k(const int* __restrict__ bhist, int NB,
                                                     int* __restrict__ bbase, int* __restrict__ cursor,
                                                     int* __restrict__ row_start, int N, int E) {
    __shared__ int tmp[256];
    int tid = threadIdx.x;
    int v = (tid < NB) ? bhist[tid] : 0;
    tmp[tid] = v;
    __syncthreads();
    for (int d = 1; d < 256; d <<= 1) {
        int t = tmp[tid];
        int a = (tid >= d) ? tmp[tid - d] : 0;
        __syncthreads();
        tmp[tid] = t + a;
        __syncthreads();
    }
    if (tid < NB) {
        int b = tmp[tid] - v;  // exclusive
        bbase[tid] = b;
        cursor[tid] = b;
    }
    if (tid == 0) {
        bbase[NB] = E;
        row_start[N] = E;
    }
}

__global__ __launch_bounds__(256) void partition_k(const int* __restrict__ src,
                                                   const int* __restrict__ dst, int E,
                                                   int* __restrict__ cursor,
                                                   unsigned int* __restrict__ part, int NB) {
    __shared__ int lh[256];
    __shared__ int lbase[256];
    for (int t = threadIdx.x; t < 256; t += 256) lh[t] = 0;
    __syncthreads();
    int per = (E + gridDim.x - 1) / gridDim.x;
    int s = blockIdx.x * per;
    int e = min(s + per, E);
    for (int i = s + threadIdx.x; i < e; i += 256) atomicAdd(&lh[dst[i] >> 9], 1);
    __syncthreads();
    for (int t = threadIdx.x; t < NB; t += 256) {
        int c = lh[t];
        lbase[t] = c ? atomicAdd(&cursor[t], c) : 0;
        lh[t] = 0;  // becomes local cursor
    }
    __syncthreads();
    for (int i = s + threadIdx.x; i < e; i += 256) {
        int d = dst[i];
        int b = d >> 9;
        int lo = atomicAdd(&lh[b], 1);
        part[lbase[b] + lo] = ((unsigned)src[i] << 9) | (unsigned)(d & 511);
    }
}

// One workgroup per bucket: per-node counts + scan in LDS -> row_start; then scatter
// src ids into the bucket's contiguous csr window (L2-resident, ~64 KB).
__global__ __launch_bounds__(512) void bucket_build_k(const unsigned int* __restrict__ part,
                                                      const int* __restrict__ bbase,
                                                      int* __restrict__ row_start,
                                                      int* __restrict__ csr, int N) {
    __shared__ int cnt[512];
    __shared__ int cur[512];
    int b = blockIdx.x, tid = threadIdx.x;
    int n0 = b << 9;
    int s = bbase[b], e2 = bbase[b + 1];
    cnt[tid] = 0;
    __syncthreads();
    for (int i = s + tid; i < e2; i += 512) atomicAdd(&cnt[part[i] & 511], 1);
    __syncthreads();
    int v = cnt[tid];
    for (int d = 1; d < 512; d <<= 1) {  // inclusive scan, in place
        int t = cnt[tid];
        int a = (tid >= d) ? cnt[tid - d] : 0;
        __syncthreads();
        cnt[tid] = t + a;
        __syncthreads();
    }
    int excl = cnt[tid] - v;
    if (n0 + tid < N) row_start[n0 + tid] = s + excl;
    cur[tid] = excl;
    __syncthreads();
    for (int i = s + tid; i < e2; i += 512) {
        unsigned u = part[i];
        int p = atomicAdd(&cur[u & 511], 1);
        csr[s + p] = (int)(u >> 9);
    }
}

// ---------------- W transpose+convert: W [K][Nc] fp32 -> WT [Nc][K] f16 ----------------

__global__ void convw_k(const float* __restrict__ W, _Float16* __restrict__ WT,
                        int K, int Nc) {
    int i = blockIdx.x * 256 + threadIdx.x;
    if (i < K * Nc) {
        int k = i / Nc, n = i % Nc;
        WT[(size_t)n * K + k] = (_Float16)W[i];
    }
}

// ---------------- GEMM1 (MFMA f16, fp32 acc): h1 = x @ W1, fused alpha1 ----------
// Block = 4 waves x 16 rows; NT=4 tiles cover Nc=64. A fp32 converted inline.
// Epilogue: h1 fp16 store + as1/ad1 from fp32 acc (head = 2t + (m16>>3), c = m16&7,
// cross-lane reduce over m16 bits 0..2).

__global__ __launch_bounds__(256) void gemm1_k(const float* __restrict__ A,
                                               const _Float16* __restrict__ BT,
                                               const float* __restrict__ a_s,
                                               const float* __restrict__ a_d,
                                               __half* __restrict__ C,
                                               float* __restrict__ os,
                                               float* __restrict__ od, int M) {
    constexpr int NT = 4, K = 512, Nc = 64;
    int wave = threadIdx.x >> 6, lane = threadIdx.x & 63;
    int m16 = lane & 15, quad = lane >> 4;
    int arow = blockIdx.x * 64 + wave * 16 + m16;
    int arc = arow < M ? arow : M - 1;
    floatx4 acc[NT] = {};
    for (int k0 = 0; k0 < K; k0 += 32) {
        const float* ap = A + (size_t)arc * K + k0 + quad * 8;
        float4 v0 = *(const float4*)ap;
        float4 v1 = *(const float4*)(ap + 4);
        half8 af;
        af[0] = (_Float16)v0.x; af[1] = (_Float16)v0.y;
        af[2] = (_Float16)v0.z; af[3] = (_Float16)v0.w;
        af[4] = (_Float16)v1.x; af[5] = (_Float16)v1.y;
        af[6] = (_Float16)v1.z; af[7] = (_Float16)v1.w;
#pragma unroll
        for (int t = 0; t < NT; ++t) {
            half8 bf = *(const half8*)(BT + (size_t)(t * 16 + m16) * K + k0 + quad * 8);
            acc[t] = __builtin_amdgcn_mfma_f32_16x16x32_f16(af, bf, acc[t], 0, 0, 0);
        }
    }
    int gm0 = blockIdx.x * 64 + wave * 16 + quad * 4;
    int head = (m16 >> 3);  // + 2t below
#pragma unroll
    for (int t = 0; t < NT; ++t) {
        float ws = a_s[(2 * t + head) * 8 + (m16 & 7)];
        float wd = a_d[(2 * t + head) * 8 + (m16 & 7)];
#pragma unroll
        for (int r = 0; r < 4; ++r) {
            int gm = gm0 + r;
            float v = acc[t][r];
            if (gm < M) C[(size_t)gm * Nc + t * 16 + m16] = __float2half(v);
            float s = v * ws, d = v * wd;
            s += __shfl_xor(s, 1, 64); d += __shfl_xor(d, 1, 64);
            s += __shfl_xor(s, 2, 64); d += __shfl_xor(d, 2, 64);
            s += __shfl_xor(s, 4, 64); d += __shfl_xor(d, 4, 64);
            if ((m16 & 7) == 0 && gm < M) {
                os[gm * 8 + 2 * t + head] = s;
                od[gm * 8 + 2 * t + head] = d;
            }
        }
    }
}

// ---------------- GEMM2 (MFMA f16, fp32 acc): h2 = h1o @ W2, fused alpha2 + fp8 pack
// NT=8 tiles cover Nc=128; tile t == head t. Epilogue: h2f8 (e4m3 pairs) store +
// as2/ad2 from fp32 acc (reduce over all 16 m16 lanes).

__global__ __launch_bounds__(256) void gemm2_k(const _Float16* __restrict__ A,
                                               const _Float16* __restrict__ BT,
                                               const float* __restrict__ a_s,
                                               const float* __restrict__ a_d,
                                               unsigned short* __restrict__ Cf8,
                                               float* __restrict__ os,
                                               float* __restrict__ od, int M) {
    constexpr int NT = 8, K = 64;
    int wave = threadIdx.x >> 6, lane = threadIdx.x & 63;
    int m16 = lane & 15, quad = lane >> 4;
    int arow = blockIdx.x * 64 + wave * 16 + m16;
    int arc = arow < M ? arow : M - 1;
    floatx4 acc[NT] = {};
    for (int k0 = 0; k0 < K; k0 += 32) {
        half8 af = *(const half8*)(A + (size_t)arc * K + k0 + quad * 8);
#pragma unroll
        for (int t = 0; t < NT; ++t) {
            half8 bf = *(const half8*)(BT + (size_t)(t * 16 + m16) * K + k0 + quad * 8);
            acc[t] = __builtin_amdgcn_mfma_f32_16x16x32_f16(af, bf, acc[t], 0, 0, 0);
        }
    }
    int gm0 = blockIdx.x * 64 + wave * 16 + quad * 4;
#pragma unroll
    for (int t = 0; t < NT; ++t) {
        float ws = a_s[t * 16 + m16];
        float wd = a_d[t * 16 + m16];
#pragma unroll
        for (int r = 0; r < 4; ++r) {
            int gm = gm0 + r;
            float v = acc[t][r];
            float o = __shfl_xor(v, 1, 64);  // neighboring column
            if (gm < M && !(m16 & 1)) {
                unsigned p = __builtin_amdgcn_cvt_pk_fp8_f32(v, o, 0, false);
                Cf8[(size_t)gm * 64 + t * 8 + (m16 >> 1)] = (unsigned short)(p & 0xffff);
            }
            float s = v * ws, d = v * wd;
            s += __shfl_xor(s, 1, 64); d += __shfl_xor(d, 1, 64);
            s += __shfl_xor(s, 2, 64); d += __shfl_xor(d, 2, 64);
            s += __shfl_xor(s, 4, 64); d += __shfl_xor(d, 4, 64);
            s += __shfl_xor(s, 8, 64); d += __shfl_xor(d, 8, 64);
            if (gm < M && m16 == t) {
                os[gm * 8 + t] = s;
                od[gm * 8 + t] = d;
            }
        }
    }
}

// ---------------- layer 1 aggregation: TWO dst nodes per wave (one per half) -------
// Half = 32 lanes; lane ll covers channels {2ll, 2ll+1} (half2), head = ll>>2.
// Batch 4 edges: lane ll computes exp for (edge ll&3, head ll>>2); broadcasts stay
// inside the half via lane index (l&32)|(head*4)|q. Every wave instr serves 2 edges.

__global__ __launch_bounds__(64) void aggregate1_k(
    const __half2* __restrict__ H1, const float* __restrict__ as,
    const float* __restrict__ ad, const int* __restrict__ row_start,
    const int* __restrict__ csr, const float* __restrict__ b1,
    __half2* __restrict__ h1o, int N) {
    int l = threadIdx.x;
    int ll = l & 31;
    int n = min(blockIdx.x * 2 + (l >> 5), N - 1);
    int h = ll >> 2;
    int jj = ll & 3;
    int hbase = (l & 32) | (ll & 28);
    float adv = ad[n * 8 + h];
    float e0 = as[n * 8 + h] + adv;
    e0 = fmaxf(e0, NEG_SLOPE * e0);
    float ex0 = __expf(e0);
    float denom = ex0;
    float2 self = __half22float2(H1[(size_t)n * 32 + ll]);
    float accx = ex0 * self.x, accy = ex0 * self.y;
    int e = row_start[n], end = row_start[n + 1];
    for (; e < end; e += 4) {
        int rem = end - e;  // >= 1
        int sj = csr[e + min(jj, rem - 1)];
        float t = as[sj * 8 + h] + adv;
        t = fmaxf(t, NEG_SLOPE * t);
        float xj = __expf(t);
        int qmax = min(rem, 4);
        for (int q = 0; q < qmax; ++q) {
            int sq = __shfl(sj, hbase + q, 64);
            float xq = __shfl(xj, hbase + q, 64);
            float2 v = __half22float2(H1[(size_t)sq * 32 + ll]);
            denom += xq;
            accx = fmaf(xq, v.x, accx);
            accy = fmaf(xq, v.y, accy);
        }
    }
    float vx = accx / denom + b1[2 * ll];
    float vy = accy / denom + b1[2 * ll + 1];
    vx = vx > 0.f ? vx : expm1f(vx);
    vy = vy > 0.f ? vy : expm1f(vy);
    h1o[(size_t)n * 32 + ll] = __floats2half2_rn(vx, vy);
}

// ---------------- layer 2 aggregation: TWO dst nodes per wave, fp8 dword gathers ---
// Lane ll covers byte-channels 4ll..4ll+3 of the 128 B fp8 row; head = ll>>2.
// Final: head-sum via shfl_xor 4/8/16 (stays in half), mean + bias, float4 store.

__global__ __launch_bounds__(64) void aggregate2_k(
    const unsigned int* __restrict__ H2, const float* __restrict__ as,
    const float* __restrict__ ad, const int* __restrict__ row_start,
    const int* __restrict__ csr, const float* __restrict__ b2,
    float* __restrict__ out, int N) {
    int l = threadIdx.x;
    int ll = l & 31;
    int n = min(blockIdx.x * 2 + (l >> 5), N - 1);
    int h = ll >> 2;
    int jj = ll & 3;
    int hbase = (l & 32) | (ll & 28);
    float adv = ad[n * 8 + h];
    float e0 = as[n * 8 + h] + adv;
    e0 = fmaxf(e0, NEG_SLOPE * e0);
    float ex0 = __expf(e0);
    float denom = ex0;
    unsigned sv = H2[(size_t)n * 32 + ll];
    floatx2 s01 = __builtin_amdgcn_cvt_pk_f32_fp8((int)sv, false);
    floatx2 s23 = __builtin_amdgcn_cvt_pk_f32_fp8((int)sv, true);
    float a0 = ex0 * s01[0], a1 = ex0 * s01[1];
    float a2 = ex0 * s23[0], a3 = ex0 * s23[1];
    int e = row_start[n], end = row_start[n + 1];
    for (; e < end; e += 4) {
        int rem = end - e;
        int sj = csr[e + min(jj, rem - 1)];
        float t = as[sj * 8 + h] + adv;
        t = fmaxf(t, NEG_SLOPE * t);
        float xj = __expf(t);
        int qmax = min(rem, 4);
        for (int q = 0; q < qmax; ++q) {
            int sq = __shfl(sj, hbase + q, 64);
            float xq = __shfl(xj, hbase + q, 64);
            unsigned gv = H2[(size_t)sq * 32 + ll];
            floatx2 v01 = __builtin_amdgcn_cvt_pk_f32_fp8((int)gv, false);
            floatx2 v23 = __builtin_amdgcn_cvt_pk_f32_fp8((int)gv, true);
            denom += xq;
            a0 = fmaf(xq, v01[0], a0);
            a1 = fmaf(xq, v01[1], a1);
            a2 = fmaf(xq, v23[0], a2);
            a3 = fmaf(xq, v23[1], a3);
        }
    }
    float inv = 1.f / denom;
    a0 *= inv; a1 *= inv; a2 *= inv; a3 *= inv;
#pragma unroll
    for (int m = 4; m <= 16; m <<= 1) {  // sum over heads (ll bits 2..4)
        a0 += __shfl_xor(a0, m, 64);
        a1 += __shfl_xor(a1, m, 64);
        a2 += __shfl_xor(a2, m, 64);
        a3 += __shfl_xor(a3, m, 64);
    }
    if (ll < 4) {
        int c0 = ll * 4;
        float4 o;
        o.x = a0 * 0.125f + b2[c0];
        o.y = a1 * 0.125f + b2[c0 + 1];
        o.z = a2 * 0.125f + b2[c0 + 2];
        o.w = a3 * 0.125f + b2[c0 + 3];
        *(float4*)(out + (size_t)n * 16 + c0) = o;
    }
}

// ---------------- launch ----------------

extern "C" void kernel_launch(void* const* d_in, const int* in_sizes, int n_in,
                              void* d_out, int out_size, void* d_ws, size_t ws_size,
                              hipStream_t stream) {
    (void)n_in; (void)out_size; (void)ws_size;
    const float* x      = (const float*)d_in[0];
    const int*   ei     = (const int*)d_in[1];
    const float* W1     = (const float*)d_in[2];
    const float* a_src1 = (const float*)d_in[3];
    const float* a_dst1 = (const float*)d_in[4];
    const float* b1     = (const float*)d_in[5];
    const float* W2     = (const float*)d_in[6];
    const float* a_src2 = (const float*)d_in[7];
    const float* a_dst2 = (const float*)d_in[8];
    const float* b2     = (const float*)d_in[9];

    int N = in_sizes[0] / 512;
    int E = in_sizes[1] / 2;
    const int* src = ei;
    const int* dst = ei + E;
    int NB = (N + 511) >> 9;  // 196 for N=100000; LDS arrays assume <= 256

    char* ws = (char*)d_ws;
    size_t off = 0;
    auto alloc = [&](size_t bytes) -> void* {
        void* p = ws + off;
        off = (off + bytes + 255) & ~(size_t)255;
        return p;
    };
    __half* h1  = (__half*)alloc((size_t)N * 64 * 2);
    __half* h1o = (__half*)alloc((size_t)N * 64 * 2);
    unsigned short* h2f8 = (unsigned short*)alloc((size_t)N * 64 * 2);  // fp8 pairs
    float* as1  = (float*)alloc((size_t)N * 8 * 4);
    float* ad1  = (float*)alloc((size_t)N * 8 * 4);
    float* as2  = (float*)alloc((size_t)N * 8 * 4);
    float* ad2  = (float*)alloc((size_t)N * 8 * 4);
    _Float16* W1T = (_Float16*)alloc((size_t)512 * 64 * 2);
    _Float16* W2T = (_Float16*)alloc((size_t)64 * 128 * 2);
    int* row_start = (int*)alloc((size_t)(N + 1) * 4);
    int* bhist     = (int*)alloc(256 * 4);
    int* bbase     = (int*)alloc(257 * 4);
    int* cursor    = (int*)alloc(256 * 4);
    unsigned int* part = (unsigned int*)alloc((size_t)E * 4);
    int* csr       = (int*)alloc((size_t)E * 4);

    // --- weight transpose+convert (tiny, L2-resident thereafter) ---
    convw_k<<<(512 * 64 + 255) / 256, 256, 0, stream>>>(W1, W1T, 512, 64);
    convw_k<<<(64 * 128 + 255) / 256, 256, 0, stream>>>(W2, W2T, 64, 128);

    // --- bucketed CSR build (shared by both layers; self-loops folded analytically) ---
    hipMemsetAsync(bhist, 0, 256 * 4, stream);
    bucket_hist_k<<<512, 256, 0, stream>>>(dst, E, bhist, NB);
    bucket_scan_k<<<1, 256, 0, stream>>>(bhist, NB, bbase, cursor, row_start, N, E);
    partition_k<<<512, 256, 0, stream>>>(src, dst, E, cursor, part, NB);
    bucket_build_k<<<NB, 512, 0, stream>>>(part, bbase, row_start, csr, N);

    int gblocks = (N + 63) / 64;
    int ablocks = (N + 1) / 2;

    // --- layer 1 ---
    gemm1_k<<<gblocks, 256, 0, stream>>>(x, W1T, a_src1, a_dst1, h1, as1, ad1, N);
    aggregate1_k<<<ablocks, 64, 0, stream>>>((const __half2*)h1, as1, ad1, row_start,
                                             csr, b1, (__half2*)h1o, N);

    // --- layer 2 ---
    gemm2_k<<<gblocks, 256, 0, stream>>>((const _Float16*)h1o, W2T, a_src2, a_dst2,
                                         h2f8, as2, ad2, N);
    aggregate2_k<<<ablocks, 64, 0, stream>>>((const unsigned int*)h2f8, as2, ad2,
                                             row_start, csr, b2, (float*)d_out, N);
}

// Round 9
// 649.771 us; speedup vs baseline: 1.1741x; 1.1741x over previous
//
#include <hip/hip_runtime.h>
#include <hip/hip_bf16.h>
#include <hip/hip_fp16.h>
#include <cstddef>

#define NEG_SLOPE 0.2f

typedef _Float16 half8 __attribute__((ext_vector_type(8)));
typedef float floatx4 __attribute__((ext_vector_type(4)));
typedef float floatx2 __attribute__((ext_vector_type(2)));

// ================= bucketed CSR build =================
// Bucket = 512 consecutive dst nodes. NB = ceil(N/512) (== 196 for N=100000, must be <= 256).
// part[] holds (src << 9) | (dst & 511) packed per edge, grouped by bucket.

__global__ __launch_bounds__(256) void bucket_hist_k(const int* __restrict__ dst, int E,
                                                     int* __restrict__ bhist, int NB) {
    __shared__ int lh[256];
    for (int t = threadIdx.x; t < 256; t += 256) lh[t] = 0;
    __syncthreads();
    int per = (E + gridDim.x - 1) / gridDim.x;
    int s = blockIdx.x * per;
    int e = min(s + per, E);
    for (int i = s + threadIdx.x; i < e; i += 256) atomicAdd(&lh[dst[i] >> 9], 1);
    __syncthreads();
    for (int t = threadIdx.x; t < NB; t += 256)
        if (lh[t]) atomicAdd(&bhist[t], lh[t]);
}

__global__ __launch_bounds__(256) void bucket_scan_k(const int* __restrict__ bhist, int NB,
                                                     int* __restrict__ bbase, int* __restrict__ cursor,
                                                     int* __restrict__ row_start, int N, int E) {
    __shared__ int tmp[256];
    int tid = threadIdx.x;
    int v = (tid < NB) ? bhist[tid] : 0;
    tmp[tid] = v;
    __syncthreads();
    for (int d = 1; d < 256; d <<= 1) {
        int t = tmp[tid];
        int a = (tid >= d) ? tmp[tid - d] : 0;
        __syncthreads();
        tmp[tid] = t + a;
        __syncthreads();
    }
    if (tid < NB) {
        int b = tmp[tid] - v;  // exclusive
        bbase[tid] = b;
        cursor[tid] = b;
    }
    if (tid == 0) {
        bbase[NB] = E;
        row_start[N] = E;
    }
}

__global__ __launch_bounds__(256) void partition_k(const int* __restrict__ src,
                                                   const int* __restrict__ dst, int E,
                                                   int* __restrict__ cursor,
                                                   unsigned int* __restrict__ part, int NB) {
    __shared__ int lh[256];
    __shared__ int lbase[256];
    for (int t = threadIdx.x; t < 256; t += 256) lh[t] = 0;
    __syncthreads();
    int per = (E + gridDim.x - 1) / gridDim.x;
    int s = blockIdx.x * per;
    int e = min(s + per, E);
    for (int i = s + threadIdx.x; i < e; i += 256) atomicAdd(&lh[dst[i] >> 9], 1);
    __syncthreads();
    for (int t = threadIdx.x; t < NB; t += 256) {
        int c = lh[t];
        lbase[t] = c ? atomicAdd(&cursor[t], c) : 0;
        lh[t] = 0;  // becomes local cursor
    }
    __syncthreads();
    for (int i = s + threadIdx.x; i < e; i += 256) {
        int d = dst[i];
        int b = d >> 9;
        int lo = atomicAdd(&lh[b], 1);
        part[lbase[b] + lo] = ((unsigned)src[i] << 9) | (unsigned)(d & 511);
    }
}

// One workgroup per bucket: per-node counts + scan in LDS -> row_start; then scatter
// src ids into the bucket's contiguous csr window (L2-resident, ~64 KB).
__global__ __launch_bounds__(512) void bucket_build_k(const unsigned int* __restrict__ part,
                                                      const int* __restrict__ bbase,
                                                      int* __restrict__ row_start,
                                                      int* __restrict__ csr, int N) {
    __shared__ int cnt[512];
    __shared__ int cur[512];
    int b = blockIdx.x, tid = threadIdx.x;
    int n0 = b << 9;
    int s = bbase[b], e2 = bbase[b + 1];
    cnt[tid] = 0;
    __syncthreads();
    for (int i = s + tid; i < e2; i += 512) atomicAdd(&cnt[part[i] & 511], 1);
    __syncthreads();
    int v = cnt[tid];
    for (int d = 1; d < 512; d <<= 1) {  // inclusive scan, in place
        int t = cnt[tid];
        int a = (tid >= d) ? cnt[tid - d] : 0;
        __syncthreads();
        cnt[tid] = t + a;
        __syncthreads();
    }
    int excl = cnt[tid] - v;
    if (n0 + tid < N) row_start[n0 + tid] = s + excl;
    cur[tid] = excl;
    __syncthreads();
    for (int i = s + tid; i < e2; i += 512) {
        unsigned u = part[i];
        int p = atomicAdd(&cur[u & 511], 1);
        csr[s + p] = (int)(u >> 9);
    }
}

// ---------------- W transpose+convert: W [K][Nc] fp32 -> WT [Nc][K] f16 ----------------

__global__ void convw_k(const float* __restrict__ W, _Float16* __restrict__ WT,
                        int K, int Nc) {
    int i = blockIdx.x * 256 + threadIdx.x;
    if (i < K * Nc) {
        int k = i / Nc, n = i % Nc;
        WT[(size_t)n * K + k] = (_Float16)W[i];
    }
}

// ---------------- GEMM1 (MFMA f16, fp32 acc): h1 = x @ W1, fused alpha1 ----------
// Block = 4 waves x 16 rows; NT=4 tiles cover Nc=64. A fp32 converted inline.
// Epilogue: h1 fp16 store + as1/ad1 from fp32 acc (head = 2t + (m16>>3), c = m16&7,
// cross-lane reduce over m16 bits 0..2).

__global__ __launch_bounds__(256) void gemm1_k(const float* __restrict__ A,
                                               const _Float16* __restrict__ BT,
                                               const float* __restrict__ a_s,
                                               const float* __restrict__ a_d,
                                               __half* __restrict__ C,
                                               float* __restrict__ os,
                                               float* __restrict__ od, int M) {
    constexpr int NT = 4, K = 512, Nc = 64;
    int wave = threadIdx.x >> 6, lane = threadIdx.x & 63;
    int m16 = lane & 15, quad = lane >> 4;
    int arow = blockIdx.x * 64 + wave * 16 + m16;
    int arc = arow < M ? arow : M - 1;
    floatx4 acc[NT] = {};
    for (int k0 = 0; k0 < K; k0 += 32) {
        const float* ap = A + (size_t)arc * K + k0 + quad * 8;
        float4 v0 = *(const float4*)ap;
        float4 v1 = *(const float4*)(ap + 4);
        half8 af;
        af[0] = (_Float16)v0.x; af[1] = (_Float16)v0.y;
        af[2] = (_Float16)v0.z; af[3] = (_Float16)v0.w;
        af[4] = (_Float16)v1.x; af[5] = (_Float16)v1.y;
        af[6] = (_Float16)v1.z; af[7] = (_Float16)v1.w;
#pragma unroll
        for (int t = 0; t < NT; ++t) {
            half8 bf = *(const half8*)(BT + (size_t)(t * 16 + m16) * K + k0 + quad * 8);
            acc[t] = __builtin_amdgcn_mfma_f32_16x16x32_f16(af, bf, acc[t], 0, 0, 0);
        }
    }
    int gm0 = blockIdx.x * 64 + wave * 16 + quad * 4;
    int head = (m16 >> 3);  // + 2t below
#pragma unroll
    for (int t = 0; t < NT; ++t) {
        float ws = a_s[(2 * t + head) * 8 + (m16 & 7)];
        float wd = a_d[(2 * t + head) * 8 + (m16 & 7)];
#pragma unroll
        for (int r = 0; r < 4; ++r) {
            int gm = gm0 + r;
            float v = acc[t][r];
            if (gm < M) C[(size_t)gm * Nc + t * 16 + m16] = __float2half(v);
            float s = v * ws, d = v * wd;
            s += __shfl_xor(s, 1, 64); d += __shfl_xor(d, 1, 64);
            s += __shfl_xor(s, 2, 64); d += __shfl_xor(d, 2, 64);
            s += __shfl_xor(s, 4, 64); d += __shfl_xor(d, 4, 64);
            if ((m16 & 7) == 0 && gm < M) {
                os[gm * 8 + 2 * t + head] = s;
                od[gm * 8 + 2 * t + head] = d;
            }
        }
    }
}

// ---------------- GEMM2 (MFMA f16, fp32 acc): h2 = h1o @ W2, fused alpha2 + fp8 pack
// NT=8 tiles cover Nc=128; tile t == head t. Epilogue: h2f8 (e4m3 pairs) store +
// as2/ad2 from fp32 acc (reduce over all 16 m16 lanes).

__global__ __launch_bounds__(256) void gemm2_k(const _Float16* __restrict__ A,
                                               const _Float16* __restrict__ BT,
                                               const float* __restrict__ a_s,
                                               const float* __restrict__ a_d,
                                               unsigned short* __restrict__ Cf8,
                                               float* __restrict__ os,
                                               float* __restrict__ od, int M) {
    constexpr int NT = 8, K = 64;
    int wave = threadIdx.x >> 6, lane = threadIdx.x & 63;
    int m16 = lane & 15, quad = lane >> 4;
    int arow = blockIdx.x * 64 + wave * 16 + m16;
    int arc = arow < M ? arow : M - 1;
    floatx4 acc[NT] = {};
    for (int k0 = 0; k0 < K; k0 += 32) {
        half8 af = *(const half8*)(A + (size_t)arc * K + k0 + quad * 8);
#pragma unroll
        for (int t = 0; t < NT; ++t) {
            half8 bf = *(const half8*)(BT + (size_t)(t * 16 + m16) * K + k0 + quad * 8);
            acc[t] = __builtin_amdgcn_mfma_f32_16x16x32_f16(af, bf, acc[t], 0, 0, 0);
        }
    }
    int gm0 = blockIdx.x * 64 + wave * 16 + quad * 4;
#pragma unroll
    for (int t = 0; t < NT; ++t) {
        float ws = a_s[t * 16 + m16];
        float wd = a_d[t * 16 + m16];
#pragma unroll
        for (int r = 0; r < 4; ++r) {
            int gm = gm0 + r;
            float v = acc[t][r];
            float o = __shfl_xor(v, 1, 64);  // neighboring column
            if (gm < M && !(m16 & 1)) {
                unsigned p = __builtin_amdgcn_cvt_pk_fp8_f32(v, o, 0, false);
                Cf8[(size_t)gm * 64 + t * 8 + (m16 >> 1)] = (unsigned short)(p & 0xffff);
            }
            float s = v * ws, d = v * wd;
            s += __shfl_xor(s, 1, 64); d += __shfl_xor(d, 1, 64);
            s += __shfl_xor(s, 2, 64); d += __shfl_xor(d, 2, 64);
            s += __shfl_xor(s, 4, 64); d += __shfl_xor(d, 4, 64);
            s += __shfl_xor(s, 8, 64); d += __shfl_xor(d, 8, 64);
            if (gm < M && m16 == t) {
                os[gm * 8 + t] = s;
                od[gm * 8 + t] = d;
            }
        }
    }
}

// ---------------- layer 1 aggregation: TWO dst nodes per wave (one per half) -------
// Half = 32 lanes; lane ll covers channels {2ll, 2ll+1} (half2), head = ll>>2.
// Main loop: 8 edges per half per iteration as two COMPILE-TIME-UNROLLED 4-batches
// (16 independent gathers in flight per wave). Dynamic-trip code only in the <=7 tail.

__global__ __launch_bounds__(64) void aggregate1_k(
    const __half2* __restrict__ H1, const float* __restrict__ as,
    const float* __restrict__ ad, const int* __restrict__ row_start,
    const int* __restrict__ csr, const float* __restrict__ b1,
    __half2* __restrict__ h1o, int N) {
    int l = threadIdx.x;
    int ll = l & 31;
    int n = min(blockIdx.x * 2 + (l >> 5), N - 1);
    int h = ll >> 2;
    int jj = ll & 3;
    int hbase = (l & 32) | (ll & 28);
    float adv = ad[n * 8 + h];
    float e0 = as[n * 8 + h] + adv;
    e0 = fmaxf(e0, NEG_SLOPE * e0);
    float ex0 = __expf(e0);
    float denom = ex0;
    float2 self = __half22float2(H1[(size_t)n * 32 + ll]);
    float accx = ex0 * self.x, accy = ex0 * self.y;
    int e = row_start[n], end = row_start[n + 1];
    for (; e + 8 <= end; e += 8) {
        int sjA = csr[e + jj];
        int sjB = csr[e + 4 + jj];
        float tA = as[sjA * 8 + h] + adv; tA = fmaxf(tA, NEG_SLOPE * tA);
        float tB = as[sjB * 8 + h] + adv; tB = fmaxf(tB, NEG_SLOPE * tB);
        float xA = __expf(tA), xB = __expf(tB);
#pragma unroll
        for (int q = 0; q < 4; ++q) {
            int sqA = __shfl(sjA, hbase + q, 64);
            float xqA = __shfl(xA, hbase + q, 64);
            float2 vA = __half22float2(H1[(size_t)sqA * 32 + ll]);
            int sqB = __shfl(sjB, hbase + q, 64);
            float xqB = __shfl(xB, hbase + q, 64);
            float2 vB = __half22float2(H1[(size_t)sqB * 32 + ll]);
            denom += xqA + xqB;
            accx = fmaf(xqA, vA.x, accx); accy = fmaf(xqA, vA.y, accy);
            accx = fmaf(xqB, vB.x, accx); accy = fmaf(xqB, vB.y, accy);
        }
    }
    while (e < end) {  // tail: <= 7 edges, <= 2 iterations
        int rem = min(end - e, 4);
        int sj = csr[e + min(jj, rem - 1)];
        float t = as[sj * 8 + h] + adv;
        t = fmaxf(t, NEG_SLOPE * t);
        float xj = __expf(t);
        for (int q = 0; q < rem; ++q) {
            int sq = __shfl(sj, hbase + q, 64);
            float xq = __shfl(xj, hbase + q, 64);
            float2 v = __half22float2(H1[(size_t)sq * 32 + ll]);
            denom += xq;
            accx = fmaf(xq, v.x, accx);
            accy = fmaf(xq, v.y, accy);
        }
        e += rem;
    }
    float vx = accx / denom + b1[2 * ll];
    float vy = accy / denom + b1[2 * ll + 1];
    vx = vx > 0.f ? vx : expm1f(vx);
    vy = vy > 0.f ? vy : expm1f(vy);
    h1o[(size_t)n * 32 + ll] = __floats2half2_rn(vx, vy);
}

// ---------------- layer 2 aggregation: TWO dst nodes per wave, fp8 dword gathers ---
// Lane ll covers byte-channels 4ll..4ll+3 of the 128 B fp8 row; head = ll>>2.
// Same unrolled 2x4-batch main loop as aggregate1_k.

__global__ __launch_bounds__(64) void aggregate2_k(
    const unsigned int* __restrict__ H2, const float* __restrict__ as,
    const float* __restrict__ ad, const int* __restrict__ row_start,
    const int* __restrict__ csr, const float* __restrict__ b2,
    float* __restrict__ out, int N) {
    int l = threadIdx.x;
    int ll = l & 31;
    int n = min(blockIdx.x * 2 + (l >> 5), N - 1);
    int h = ll >> 2;
    int jj = ll & 3;
    int hbase = (l & 32) | (ll & 28);
    float adv = ad[n * 8 + h];
    float e0 = as[n * 8 + h] + adv;
    e0 = fmaxf(e0, NEG_SLOPE * e0);
    float ex0 = __expf(e0);
    float denom = ex0;
    unsigned sv = H2[(size_t)n * 32 + ll];
    floatx2 s01 = __builtin_amdgcn_cvt_pk_f32_fp8((int)sv, false);
    floatx2 s23 = __builtin_amdgcn_cvt_pk_f32_fp8((int)sv, true);
    float a0 = ex0 * s01[0], a1 = ex0 * s01[1];
    float a2 = ex0 * s23[0], a3 = ex0 * s23[1];
    int e = row_start[n], end = row_start[n + 1];
    for (; e + 8 <= end; e += 8) {
        int sjA = csr[e + jj];
        int sjB = csr[e + 4 + jj];
        float tA = as[sjA * 8 + h] + adv; tA = fmaxf(tA, NEG_SLOPE * tA);
        float tB = as[sjB * 8 + h] + adv; tB = fmaxf(tB, NEG_SLOPE * tB);
        float xA = __expf(tA), xB = __expf(tB);
#pragma unroll
        for (int q = 0; q < 4; ++q) {
            int sqA = __shfl(sjA, hbase + q, 64);
            float xqA = __shfl(xA, hbase + q, 64);
            unsigned gvA = H2[(size_t)sqA * 32 + ll];
            int sqB = __shfl(sjB, hbase + q, 64);
            float xqB = __shfl(xB, hbase + q, 64);
            unsigned gvB = H2[(size_t)sqB * 32 + ll];
            floatx2 vA01 = __builtin_amdgcn_cvt_pk_f32_fp8((int)gvA, false);
            floatx2 vA23 = __builtin_amdgcn_cvt_pk_f32_fp8((int)gvA, true);
            floatx2 vB01 = __builtin_amdgcn_cvt_pk_f32_fp8((int)gvB, false);
            floatx2 vB23 = __builtin_amdgcn_cvt_pk_f32_fp8((int)gvB, true);
            denom += xqA + xqB;
            a0 = fmaf(xqA, vA01[0], a0); a1 = fmaf(xqA, vA01[1], a1);
            a2 = fmaf(xqA, vA23[0], a2); a3 = fmaf(xqA, vA23[1], a3);
            a0 = fmaf(xqB, vB01[0], a0); a1 = fmaf(xqB, vB01[1], a1);
            a2 = fmaf(xqB, vB23[0], a2); a3 = fmaf(xqB, vB23[1], a3);
        }
    }
    while (e < end) {  // tail: <= 7 edges, <= 2 iterations
        int rem = min(end - e, 4);
        int sj = csr[e + min(jj, rem - 1)];
        float t = as[sj * 8 + h] + adv;
        t = fmaxf(t, NEG_SLOPE * t);
        float xj = __expf(t);
        for (int q = 0; q < rem; ++q) {
            int sq = __shfl(sj, hbase + q, 64);
            float xq = __shfl(xj, hbase + q, 64);
            unsigned gv = H2[(size_t)sq * 32 + ll];
            floatx2 v01 = __builtin_amdgcn_cvt_pk_f32_fp8((int)gv, false);
            floatx2 v23 = __builtin_amdgcn_cvt_pk_f32_fp8((int)gv, true);
            denom += xq;
            a0 = fmaf(xq, v01[0], a0); a1 = fmaf(xq, v01[1], a1);
            a2 = fmaf(xq, v23[0], a2); a3 = fmaf(xq, v23[1], a3);
        }
        e += rem;
    }
    float inv = 1.f / denom;
    a0 *= inv; a1 *= inv; a2 *= inv; a3 *= inv;
#pragma unroll
    for (int m = 4; m <= 16; m <<= 1) {  // sum over heads (ll bits 2..4)
        a0 += __shfl_xor(a0, m, 64);
        a1 += __shfl_xor(a1, m, 64);
        a2 += __shfl_xor(a2, m, 64);
        a3 += __shfl_xor(a3, m, 64);
    }
    if (ll < 4) {
        int c0 = ll * 4;
        float4 o;
        o.x = a0 * 0.125f + b2[c0];
        o.y = a1 * 0.125f + b2[c0 + 1];
        o.z = a2 * 0.125f + b2[c0 + 2];
        o.w = a3 * 0.125f + b2[c0 + 3];
        *(float4*)(out + (size_t)n * 16 + c0) = o;
    }
}

// ---------------- launch ----------------

extern "C" void kernel_launch(void* const* d_in, const int* in_sizes, int n_in,
                              void* d_out, int out_size, void* d_ws, size_t ws_size,
                              hipStream_t stream) {
    (void)n_in; (void)out_size; (void)ws_size;
    const float* x      = (const float*)d_in[0];
    const int*   ei     = (const int*)d_in[1];
    const float* W1     = (const float*)d_in[2];
    const float* a_src1 = (const float*)d_in[3];
    const float* a_dst1 = (const float*)d_in[4];
    const float* b1     = (const float*)d_in[5];
    const float* W2     = (const float*)d_in[6];
    const float* a_src2 = (const float*)d_in[7];
    const float* a_dst2 = (const float*)d_in[8];
    const float* b2     = (const float*)d_in[9];

    int N = in_sizes[0] / 512;
    int E = in_sizes[1] / 2;
    const int* src = ei;
    const int* dst = ei + E;
    int NB = (N + 511) >> 9;  // 196 for N=100000; LDS arrays assume <= 256

    char* ws = (char*)d_ws;
    size_t off = 0;
    auto alloc = [&](size_t bytes) -> void* {
        void* p = ws + off;
        off = (off + bytes + 255) & ~(size_t)255;
        return p;
    };
    __half* h1  = (__half*)alloc((size_t)N * 64 * 2);
    __half* h1o = (__half*)alloc((size_t)N * 64 * 2);
    unsigned short* h2f8 = (unsigned short*)alloc((size_t)N * 64 * 2);  // fp8 pairs
    float* as1  = (float*)alloc((size_t)N * 8 * 4);
    float* ad1  = (float*)alloc((size_t)N * 8 * 4);
    float* as2  = (float*)alloc((size_t)N * 8 * 4);
    float* ad2  = (float*)alloc((size_t)N * 8 * 4);
    _Float16* W1T = (_Float16*)alloc((size_t)512 * 64 * 2);
    _Float16* W2T = (_Float16*)alloc((size_t)64 * 128 * 2);
    int* row_start = (int*)alloc((size_t)(N + 1) * 4);
    int* bhist     = (int*)alloc(256 * 4);
    int* bbase     = (int*)alloc(257 * 4);
    int* cursor    = (int*)alloc(256 * 4);
    unsigned int* part = (unsigned int*)alloc((size_t)E * 4);
    int* csr       = (int*)alloc((size_t)E * 4);

    // --- weight transpose+convert (tiny, L2-resident thereafter) ---
    convw_k<<<(512 * 64 + 255) / 256, 256, 0, stream>>>(W1, W1T, 512, 64);
    convw_k<<<(64 * 128 + 255) / 256, 256, 0, stream>>>(W2, W2T, 64, 128);

    // --- bucketed CSR build (shared by both layers; self-loops folded analytically) ---
    hipMemsetAsync(bhist, 0, 256 * 4, stream);
    bucket_hist_k<<<512, 256, 0, stream>>>(dst, E, bhist, NB);
    bucket_scan_k<<<1, 256, 0, stream>>>(bhist, NB, bbase, cursor, row_start, N, E);
    partition_k<<<512, 256, 0, stream>>>(src, dst, E, cursor, part, NB);
    bucket_build_k<<<NB, 512, 0, stream>>>(part, bbase, row_start, csr, N);

    int gblocks = (N + 63) / 64;
    int ablocks = (N + 1) / 2;

    // --- layer 1 ---
    gemm1_k<<<gblocks, 256, 0, stream>>>(x, W1T, a_src1, a_dst1, h1, as1, ad1, N);
    aggregate1_k<<<ablocks, 64, 0, stream>>>((const __half2*)h1, as1, ad1, row_start,
                                             csr, b1, (__half2*)h1o, N);

    // --- layer 2 ---
    gemm2_k<<<gblocks, 256, 0, stream>>>((const _Float16*)h1o, W2T, a_src2, a_dst2,
                                         h2f8, as2, ad2, N);
    aggregate2_k<<<ablocks, 64, 0, stream>>>((const unsigned int*)h2f8, as2, ad2,
                                             row_start, csr, b2, (float*)d_out, N);
}